// Round 1
// baseline (137.537 us; speedup 1.0000x reference)
//
#include <hip/hip_runtime.h>
#include <hip/hip_bf16.h>

// FourierKANLayer: out[n,o] = bias[o] + sum_{i,b} coeffs[o,i,b] * basis[n,i,b]
// basis = [1, sin(m*pi*x) m=1..32, cos(m*pi*x) m=1..32] per (n,i).
// Strategy: bf16 MFMA GEMM with K=4096 (mode-major, sin/cos interleaved),
// A generated in registers via angle-addition recurrence, B repacked into
// MFMA fragment order, ones-basis folded into bias.

typedef __bf16 bf16x8 __attribute__((ext_vector_type(8)));
typedef float  f32x4  __attribute__((ext_vector_type(4)));

#define NROWS 65536
#define PI_F 3.14159265358979323846f

// ---------------------------------------------------------------------------
// Repack coeffs [64][64][65] fp32 -> Bp bf16 in B-fragment order.
// k = m*128 + j*32 + q*8 + t  (m=mode-1 in [0,32), j k-chunk, q=lane>>4, t in [0,8))
//   i = j*16 + q*4 + (t>>1);  t even -> sin (b=1+m), t odd -> cos (b=33+m)
// frag id = (m*4 + j)*4 + c ; col o = c*16 + (lane&15)
// Bp[frag*512 + lane*8 + t] = coeffs[o][i][b]
// Also bias2[o] = bias[o] + sum_i coeffs[o][i][0].
// ---------------------------------------------------------------------------
__global__ __launch_bounds__(256) void fkan_repack(
    const float* __restrict__ coeffs, const float* __restrict__ bias,
    __bf16* __restrict__ Bp, float* __restrict__ bias2) {
  int gid = blockIdx.x * 256 + threadIdx.x;   // 0 .. 262143
  int t    = gid & 7;
  int lane = (gid >> 3) & 63;
  int frag = gid >> 9;                        // 0..511
  int c = frag & 3;
  int j = (frag >> 2) & 3;
  int m = frag >> 4;                          // 0..31
  int q  = lane >> 4;
  int nl = lane & 15;
  int i = j * 16 + q * 4 + (t >> 1);
  int o = c * 16 + nl;
  int b = (t & 1) ? (33 + m) : (1 + m);
  Bp[gid] = (__bf16)coeffs[(o * 64 + i) * 65 + b];

  if (gid < 64) {
    float s = bias[gid];
    for (int ii = 0; ii < 64; ++ii) s += coeffs[(gid * 64 + ii) * 65 + 0];
    bias2[gid] = s;
  }
}

// ---------------------------------------------------------------------------
// Main kernel: 256 threads = 4 waves; block handles 64 rows x 64 cols.
// Wave w: rows [blk*64 + w*16, +16). Lane: row = lane&15, quad q = lane>>4.
// Lane owns 16 (row,i) recurrences: i = j*16 + q*4 + e, j,e in [0,4).
// Per mode: build 4 A-frags in regs, MFMA against 16 B-frags from LDS.
// ---------------------------------------------------------------------------
__global__ __launch_bounds__(256) void fkan_main(
    const float* __restrict__ x, const __bf16* __restrict__ Bp,
    const float* __restrict__ bias2, float* __restrict__ out) {
  __shared__ __bf16 Bs[2][8192];   // 2 x 16 KB (one mode-slice of B)

  int tid  = threadIdx.x;
  int wave = tid >> 6;
  int lane = tid & 63;
  int q    = lane >> 4;
  int rl   = lane & 15;
  int row  = blockIdx.x * 64 + wave * 16 + rl;

  // --- load x and compute sin/cos(pi*x) for the lane's 16 i's -------------
  float s1[16], c1[16], sm[16], cm[16];
  const float* xrow = x + (size_t)row * 64;
  #pragma unroll
  for (int j = 0; j < 4; ++j) {
    f32x4 v = *(const f32x4*)(xrow + j * 16 + q * 4);
    #pragma unroll
    for (int e = 0; e < 4; ++e) {
      float ss, cc;
      __sincosf(PI_F * v[e], &ss, &cc);
      s1[j * 4 + e] = ss;  c1[j * 4 + e] = cc;   // rotation step (mode 1)
      sm[j * 4 + e] = ss;  cm[j * 4 + e] = cc;   // current state (mode 1)
    }
  }

  f32x4 acc[4];
  #pragma unroll
  for (int c = 0; c < 4; ++c) acc[c] = (f32x4){0.f, 0.f, 0.f, 0.f};

  // --- stage mode 0 B-slice ----------------------------------------------
  {
    const f32x4* src = (const f32x4*)Bp;
    f32x4* dst = (f32x4*)(&Bs[0][0]);
    #pragma unroll
    for (int k = 0; k < 4; ++k) dst[k * 256 + tid] = src[k * 256 + tid];
  }
  __syncthreads();

  for (int m = 0; m < 32; ++m) {
    int nb = m & 1;
    // prefetch next mode's B-slice into the other buffer
    if (m < 31) {
      const f32x4* src = (const f32x4*)(Bp + (size_t)(m + 1) * 8192);
      f32x4* dst = (f32x4*)(&Bs[nb ^ 1][0]);
      #pragma unroll
      for (int k = 0; k < 4; ++k) dst[k * 256 + tid] = src[k * 256 + tid];
    }

    // MFMA over this mode's 128-wide K-slice
    #pragma unroll
    for (int j = 0; j < 4; ++j) {
      bf16x8 af;
      #pragma unroll
      for (int e = 0; e < 4; ++e) {
        af[2 * e]     = (__bf16)sm[j * 4 + e];
        af[2 * e + 1] = (__bf16)cm[j * 4 + e];
      }
      #pragma unroll
      for (int c = 0; c < 4; ++c) {
        const bf16x8* bf =
            (const bf16x8*)(&Bs[nb][(j * 4 + c) * 512 + lane * 8]);
        acc[c] = __builtin_amdgcn_mfma_f32_16x16x32_bf16(af, *bf, acc[c],
                                                         0, 0, 0);
      }
    }

    // advance recurrence: (s,c) <- (s*c1 + c*s1, c*c1 - s*s1)
    #pragma unroll
    for (int p = 0; p < 16; ++p) {
      float ns = fmaf(sm[p], c1[p],  cm[p] * s1[p]);
      float nc = fmaf(cm[p], c1[p], -sm[p] * s1[p]);
      sm[p] = ns;  cm[p] = nc;
    }
    __syncthreads();
  }

  // --- epilogue: C/D layout col=lane&15, row=q*4+reg (m89-verified) -------
  float b2[4];
  #pragma unroll
  for (int c = 0; c < 4; ++c) b2[c] = bias2[c * 16 + rl];
  int orow = blockIdx.x * 64 + wave * 16 + q * 4;
  #pragma unroll
  for (int c = 0; c < 4; ++c) {
    #pragma unroll
    for (int r = 0; r < 4; ++r) {
      out[(size_t)(orow + r) * 64 + c * 16 + rl] = acc[c][r] + b2[c];
    }
  }
}

extern "C" void kernel_launch(void* const* d_in, const int* in_sizes, int n_in,
                              void* d_out, int out_size, void* d_ws, size_t ws_size,
                              hipStream_t stream) {
  const float* x      = (const float*)d_in[0];   // [65536, 64]
  const float* coeffs = (const float*)d_in[1];   // [64, 64, 65]
  const float* bias   = (const float*)d_in[2];   // [64]
  float* out = (float*)d_out;

  // workspace layout: Bp (512 KB bf16) | bias2 (256 B fp32)
  __bf16* Bp   = (__bf16*)d_ws;
  float* bias2 = (float*)((char*)d_ws + 512 * 1024);

  int n_rows = in_sizes[0] / 64;                 // 65536

  fkan_repack<<<1024, 256, 0, stream>>>(coeffs, bias, Bp, bias2);
  fkan_main<<<n_rows / 64, 256, 0, stream>>>(x, Bp, bias2, out);
}

// Round 2
// 113.962 us; speedup vs baseline: 1.2069x; 1.2069x over previous
//
#include <hip/hip_runtime.h>
#include <hip/hip_bf16.h>

// FourierKANLayer: out[n,o] = bias[o] + sum_{i,b} coeffs[o,i,b] * basis[n,i,b]
// basis = [1, sin(m*pi*x) m=1..32, cos(m*pi*x) m=1..32] per (n,i).
//
// R1 design: 32x32x16 bf16 MFMA, 32 rows/wave (halves LDS B-read per FLOP vs
// 16 rows/wave), Chebyshev recurrence (2 fma per sin/cos pair per mode),
// global_load_lds(16B) staging, double-buffered, 128 rows/block, grid=512.

typedef __bf16 bf16x8 __attribute__((ext_vector_type(8)));
typedef float  f32x4  __attribute__((ext_vector_type(4)));
typedef float  f32x16 __attribute__((ext_vector_type(16)));

#define PI_F 3.14159265358979323846f

// ---------------------------------------------------------------------------
// Repack coeffs [64][64][65] fp32 -> Bp bf16 in 32x32x16 B-fragment order.
// frag = (m*8 + kc)*2 + cc   (m=mode-1 in [0,32), kc in [0,8), cc in [0,2))
// lane: col o = cc*32 + (lane&31), kq = lane>>5
// t in [0,8): k_local = kc*16 + kq*8 + t; i = kc*8 + kq*4 + (t>>1)
//             b = (t&1) ? 33+m : 1+m
// Bp[frag*512 + lane*8 + t] = coeffs[o][i][b]
// One thread per (frag,lane): reads 8 floats, writes 16 B contiguous.
// bias2[o] = bias[o] + sum_i coeffs[o][i][0]  (block 0, threads 0..63).
// ---------------------------------------------------------------------------
__global__ __launch_bounds__(256) void fkan_repack(
    const float* __restrict__ coeffs, const float* __restrict__ bias,
    __bf16* __restrict__ Bp, float* __restrict__ bias2) {
  int gid  = blockIdx.x * 256 + threadIdx.x;   // 0 .. 32767
  int lane = gid & 63;
  int frag = gid >> 6;                          // 0..511
  int m  = frag >> 4;
  int kc = (frag >> 1) & 7;
  int cc = frag & 1;
  int o  = cc * 32 + (lane & 31);
  int kq = lane >> 5;

  bf16x8 v;
  #pragma unroll
  for (int t = 0; t < 8; ++t) {
    int i = kc * 8 + kq * 4 + (t >> 1);
    int b = (t & 1) ? (33 + m) : (1 + m);
    v[t] = (__bf16)coeffs[(o * 64 + i) * 65 + b];
  }
  *(bf16x8*)(Bp + (size_t)frag * 512 + lane * 8) = v;

  if (blockIdx.x == 0 && threadIdx.x < 64) {
    int oo = threadIdx.x;
    float s = bias[oo];
    #pragma unroll 4
    for (int ii = 0; ii < 64; ++ii) s += coeffs[(oo * 64 + ii) * 65 + 0];
    bias2[oo] = s;
  }
}

// ---------------------------------------------------------------------------
// Main kernel: 256 threads = 4 waves; block = 128 rows x 64 cols.
// Wave w: rows [blk*128 + w*32, +32). Lane: row = lane&31, kq = lane>>5.
// Lane owns 32 Chebyshev instances: (row, i = kc*8 + kq*4 + e), kc,e in [0,8)x[0,4).
// Per mode: 8 A-frags built in regs, 16 B-frags (ds_read_b128) from LDS,
// 16 MFMA 32x32x16. Chebyshev advance: 2 fma per instance per mode.
// ---------------------------------------------------------------------------
__device__ __forceinline__ void stage_slice(const __bf16* __restrict__ Bp,
                                            __bf16* dst, int m, int wave,
                                            int lane) {
  const char* g = (const char*)Bp + (size_t)m * 16384 + wave * 4096 + lane * 16;
  char* l = (char*)dst + wave * 4096;
  #pragma unroll
  for (int r = 0; r < 4; ++r) {
    __builtin_amdgcn_global_load_lds(
        (const __attribute__((address_space(1))) void*)(g + r * 1024),
        (__attribute__((address_space(3))) void*)(l + r * 1024), 16, 0, 0);
  }
}

__global__ __launch_bounds__(256, 2) void fkan_main(
    const float* __restrict__ x, const __bf16* __restrict__ Bp,
    const float* __restrict__ bias2, float* __restrict__ out) {
  __shared__ __bf16 Bs[2][8192];   // 2 x 16 KB double buffer

  int tid  = threadIdx.x;
  int wave = tid >> 6;
  int lane = tid & 63;
  int kq   = lane >> 5;            // which K-half of the frag this lane holds
  int cl   = lane & 31;
  int row  = blockIdx.x * 128 + wave * 32 + cl;

  // --- init: sincos(pi*x) for the lane's 32 (row,i) instances -------------
  float T[32], sp[32], cp[32], sc[32], cc_[32];
  const float* xrow = x + (size_t)row * 64 + kq * 4;
  #pragma unroll
  for (int kc = 0; kc < 8; ++kc) {
    f32x4 v = *(const f32x4*)(xrow + kc * 8);
    #pragma unroll
    for (int e = 0; e < 4; ++e) {
      int p = kc * 4 + e;
      float ss, cs;
      __sincosf(PI_F * v[e], &ss, &cs);
      T[p] = 2.0f * cs;          // Chebyshev multiplier
      sc[p] = ss;  cc_[p] = cs;  // current  = mode 1
      sp[p] = 0.f; cp[p] = 1.f;  // previous = mode 0
    }
  }

  f32x16 acc[2];
  #pragma unroll
  for (int c2 = 0; c2 < 2; ++c2)
    #pragma unroll
    for (int r = 0; r < 16; ++r) acc[c2][r] = 0.f;

  stage_slice(Bp, &Bs[0][0], 0, wave, lane);
  __syncthreads();

  // --- mode loop, unrolled by 2 (Chebyshev double-buffer, no reg moves) ---
  for (int m = 0; m < 32; m += 2) {
    // ---- mode m (values in sc/cc_), B in Bs[0]; prefetch m+1 -> Bs[1]
    if (m + 1 < 32) stage_slice(Bp, &Bs[1][0], m + 1, wave, lane);
    #pragma unroll
    for (int kc = 0; kc < 8; ++kc) {
      bf16x8 af;
      #pragma unroll
      for (int e = 0; e < 4; ++e) {
        af[2 * e]     = (__bf16)sc[kc * 4 + e];
        af[2 * e + 1] = (__bf16)cc_[kc * 4 + e];
      }
      #pragma unroll
      for (int c2 = 0; c2 < 2; ++c2) {
        bf16x8 bf = *(const bf16x8*)(&Bs[0][(kc * 2 + c2) * 512 + lane * 8]);
        acc[c2] = __builtin_amdgcn_mfma_f32_32x32x16_bf16(af, bf, acc[c2],
                                                          0, 0, 0);
      }
    }
    #pragma unroll
    for (int p = 0; p < 32; ++p) {   // advance: prev <- next
      sp[p] = fmaf(T[p], sc[p], -sp[p]);
      cp[p] = fmaf(T[p], cc_[p], -cp[p]);
    }
    __syncthreads();

    // ---- mode m+1 (values in sp/cp), B in Bs[1]; prefetch m+2 -> Bs[0]
    if (m + 2 < 32) stage_slice(Bp, &Bs[0][0], m + 2, wave, lane);
    #pragma unroll
    for (int kc = 0; kc < 8; ++kc) {
      bf16x8 af;
      #pragma unroll
      for (int e = 0; e < 4; ++e) {
        af[2 * e]     = (__bf16)sp[kc * 4 + e];
        af[2 * e + 1] = (__bf16)cp[kc * 4 + e];
      }
      #pragma unroll
      for (int c2 = 0; c2 < 2; ++c2) {
        bf16x8 bf = *(const bf16x8*)(&Bs[1][(kc * 2 + c2) * 512 + lane * 8]);
        acc[c2] = __builtin_amdgcn_mfma_f32_32x32x16_bf16(af, bf, acc[c2],
                                                          0, 0, 0);
      }
    }
    #pragma unroll
    for (int p = 0; p < 32; ++p) {
      sc[p]  = fmaf(T[p], sp[p], -sc[p]);
      cc_[p] = fmaf(T[p], cp[p], -cc_[p]);
    }
    __syncthreads();
  }

  // --- epilogue: C/D layout col=lane&31, row=(r&3)+8*(r>>2)+4*(lane>>5) ---
  float* orow = out + (size_t)(blockIdx.x * 128 + wave * 32) * 64;
  #pragma unroll
  for (int c2 = 0; c2 < 2; ++c2) {
    float b2 = bias2[c2 * 32 + cl];
    #pragma unroll
    for (int r = 0; r < 16; ++r) {
      int ro = (r & 3) + 8 * (r >> 2) + 4 * kq;
      orow[(size_t)ro * 64 + c2 * 32 + cl] = acc[c2][r] + b2;
    }
  }
}

extern "C" void kernel_launch(void* const* d_in, const int* in_sizes, int n_in,
                              void* d_out, int out_size, void* d_ws, size_t ws_size,
                              hipStream_t stream) {
  const float* x      = (const float*)d_in[0];   // [65536, 64]
  const float* coeffs = (const float*)d_in[1];   // [64, 64, 65]
  const float* bias   = (const float*)d_in[2];   // [64]
  float* out = (float*)d_out;

  __bf16* Bp   = (__bf16*)d_ws;                  // 512 KB
  float* bias2 = (float*)((char*)d_ws + 512 * 1024);

  int n_rows = in_sizes[0] / 64;                 // 65536

  fkan_repack<<<128, 256, 0, stream>>>(coeffs, bias, Bp, bias2);
  fkan_main<<<n_rows / 128, 256, 0, stream>>>(x, Bp, bias2, out);
}